// Round 6
// baseline (233.233 us; speedup 1.0000x reference)
//
#include <hip/hip_runtime.h>

typedef __attribute__((ext_vector_type(8))) short short8;
typedef __attribute__((ext_vector_type(4))) float f32x4;
typedef unsigned long long ull;

#define NN 4800
#define NN1 4801
#define NC 240
#define CL 20
#define KLEN 600

__device__ __forceinline__ short bf16rne(float x) {
    unsigned u = __float_as_uint(x);
    u = (u + 0x7FFFu + ((u >> 16) & 1u)) >> 16;
    return (short)u;
}
// monotonic float->uint key (ascending float == ascending uint)
__device__ __forceinline__ unsigned fkey(float f) {
    unsigned i = __float_as_uint(f);
    return (i & 0x80000000u) ? ~i : (i | 0x80000000u);
}

// ---------- prep: h1 (single pass, fused with s1/t1 dots), weight transposes, mask copy, out zero ----------
__global__ __launch_bounds__(256) void prep(
    const float* __restrict__ flat, const float* __restrict__ amask,
    const float* __restrict__ W1, const float* __restrict__ as1, const float* __restrict__ ad1,
    const float* __restrict__ W2, const float* __restrict__ P1, const float* __restrict__ P2,
    float* __restrict__ h1, float* __restrict__ s1, float* __restrict__ t1,
    short* __restrict__ W2T, short* __restrict__ P1T, short* __restrict__ P2T,
    float* __restrict__ out) {
    const int gtid = blockIdx.x * 256 + threadIdx.x;
    const int GT = 1200 * 256;
    for (int x = gtid; x < 109280; x += GT) {
        if (x < 73728) {                       // W2T [384][192]
            int n = x / 192, k = x % 192;
            W2T[x] = bf16rne(W2[k * 384 + n]);
        } else if (x < 94208) {                // P1T [128][160] (zero-padded K)
            int z = x - 73728; int n = z / 160, k = z % 160;
            P1T[z] = bf16rne(k < 143 ? P1[k * 128 + n] : 0.f);
        } else if (x < 102400) {               // P2T [64][128]
            int z = x - 94208; int n = z / 128, k = z % 128;
            P2T[z] = bf16rne(P2[k * 64 + n]);
        } else if (x < 107232) {               // mask passthrough (4832)
            int m = x - 102400;
            out[2048 + m] = amask[m];
        } else {
            out[x - 107232] = 0.f;             // pool accumulators (2048)
        }
    }
    const int lane = threadIdx.x & 63;
    const int gw = (gtid >> 6);
    for (int task = gw; task < 3 * NN; task += (GT >> 6)) {
        int h = task / NN, i = task % NN;
        int col = h * 64 + lane;
        const float* fr = flat + i * 15;
        float hv = 0.f;
#pragma unroll
        for (int f = 0; f < 15; ++f) hv += fr[f] * W1[f * 192 + col];
        h1[i * 192 + col] = hv;                // single h1 pass
        float ps = hv * as1[col], pt = hv * ad1[col];
#pragma unroll
        for (int off = 32; off; off >>= 1) { ps += __shfl_xor(ps, off); pt += __shfl_xor(pt, off); }
        if (lane == 0) { s1[h * NN + i] = ps; t1[h * NN + i] = pt; }
    }
}

// ---------- sortk: bitonic-sort each 600-key chunk (composite key fkey<<32|global_idx). grid (8,3) ----------
__global__ __launch_bounds__(256) void sortk(const float* __restrict__ t, ull* __restrict__ sortedK) {
    __shared__ ull ls[1024];
    const int kc = blockIdx.x, h = blockIdx.y, tid = threadIdx.x;
    const float* tp = t + h * NN + kc * KLEN;
    for (int i = tid; i < 1024; i += 256)
        ls[i] = (i < KLEN) ? (((ull)fkey(tp[i]) << 32) | (unsigned)(kc * KLEN + i)) : ~0ull;
    __syncthreads();
    for (int k = 2; k <= 1024; k <<= 1) {
        for (int j = k >> 1; j > 0; j >>= 1) {
            for (int i = tid; i < 1024; i += 256) {
                int p = i ^ j;
                if (p > i) {
                    ull a = ls[i], b = ls[p];
                    bool up = ((i & k) == 0);
                    if ((a > b) == up) { ls[i] = b; ls[p] = a; }
                }
            }
            __syncthreads();
        }
    }
    ull* dst = sortedK + (h * 8 + kc) * KLEN;
    for (int i = tid; i < KLEN; i += 256) dst[i] = ls[i];
}

// ---------- kranksc: rank via binary search over sorted chunks + direct scatter. grid (38,3) ----------
// q < NN : rank of t_q (strict composite order == value order with global-idx tiebreak) -> inv/e1s/e2s
// q >= NN: #{j : t_j <= -s_i} via low-word all-ones (counts all value-ties)           -> rks
__global__ __launch_bounds__(256) void kranksc(const float* __restrict__ s, const float* __restrict__ t,
                                               const ull* __restrict__ sortedK,
                                               int* __restrict__ inv, float* __restrict__ e1s,
                                               float* __restrict__ e2s, int* __restrict__ rks) {
    __shared__ __align__(16) ull ts[KLEN];
    const int h = blockIdx.y, tid = threadIdx.x;
    const int q = blockIdx.x * 256 + tid;
    const bool active = q < 2 * NN;
    ull uq = 0; float tv = 0.f;
    if (active) {
        if (q < NN) { tv = t[h * NN + q]; uq = ((ull)fkey(tv) << 32) | (unsigned)q; }
        else        { uq = ((ull)fkey(-s[h * NN + q - NN]) << 32) | 0xFFFFFFFFu; }
    }
    int rank = 0;
    for (int kc = 0; kc < 8; ++kc) {
        __syncthreads();                       // previous-iteration readers done
        const ull* src = sortedK + (h * 8 + kc) * KLEN;
        for (int k = tid; k < KLEN; k += 256) ts[k] = src[k];
        __syncthreads();
        if (active) {
            int pos = 0;
#pragma unroll
            for (int st = 512; st; st >>= 1)
                if (pos + st <= KLEN && ts[pos + st - 1] < uq) pos += st;
            rank += pos;
        }
    }
    if (!active) return;
    if (q < NN) {
        inv[h * NN + rank] = q;
        e1s[h * NN + rank] = __expf(tv);
        e2s[h * NN + rank] = __expf(0.2f * tv);
    } else {
        rks[h * NN + q - NN] = rank;
    }
}

// ---------- phA: chunk totals. grid (NC/PACK, 3), PACK*Dd == 256 ----------
template <int Dd, int HD, int PACK>
__global__ __launch_bounds__(256) void phA(const float* __restrict__ hsrc, const int* __restrict__ inv,
                                           const float* __restrict__ e1s, const float* __restrict__ e2s,
                                           float* __restrict__ T1, float* __restrict__ T2) {
    __shared__ int inv_l[PACK * CL];
    __shared__ float w1s[PACK * CL], w2s[PACK * CL];
    const int h = blockIdx.y, tid = threadIdx.x;
    const int base = blockIdx.x * (PACK * CL);
    if (tid < PACK * CL) {
        inv_l[tid] = inv[h * NN + base + tid];
        w1s[tid] = e1s[h * NN + base + tid];
        w2s[tid] = e2s[h * NN + base + tid];
    }
    __syncthreads();
    const int sub = tid / Dd, d = tid % Dd;
    const int c = blockIdx.x * PACK + sub;
    float a1 = 0.f, a2 = 0.f;
#pragma unroll
    for (int p = 0; p < CL; ++p) {
        int j = inv_l[sub * CL + p];
        float hv = hsrc[(size_t)j * HD + h * Dd + d];
        a1 += w1s[sub * CL + p] * hv;
        a2 += w2s[sub * CL + p] * hv;
    }
    T1[(h * NC + c) * Dd + d] = a1;
    T2[(h * NC + c) * Dd + d] = a2;
}

// ---------- phBden: PARALLEL Tot scans (segmented, 8x30) + denominator scans ----------
// blocks [0, 6*G): one per (h, dir, 32-wide d-group); blocks [6*G, 6*G+3): den scans per head.
template <int Dd>
__global__ __launch_bounds__(256) void phBden(const float* __restrict__ T1, const float* __restrict__ T2,
                                              const float* __restrict__ e1s, const float* __restrict__ e2s,
                                              float* __restrict__ O1, float* __restrict__ O2,
                                              float* __restrict__ DenS1, float* __restrict__ DenP2) {
    constexpr int G = Dd / 32;
    constexpr int NSCAN = 6 * G;
    __shared__ __align__(16) float smem[9608];      // union: scan{ls 7680 + sbd 512} | den{l1 4800, l2 4800, wsum 8}
    const int tid = threadIdx.x;
    if (blockIdx.x < NSCAN) {
        float (*ls)[32] = (float(*)[32])smem;        // [240][32]
        double* sbd = (double*)(smem + 7680);        // [8][32] segment sums
        const int b = blockIdx.x;
        const int h = b % 3, rest = b / 3, dir = rest & 1, dg = rest >> 1;
        const float* T = dir ? T2 : T1;
        for (int idx = tid; idx < NC * 32; idx += 256) {
            int c = idx >> 5, dl = idx & 31;
            ls[c][dl] = T[(h * NC + c) * Dd + dg * 32 + dl];
        }
        __syncthreads();
        const int seg = tid >> 5, dl = tid & 31;     // 8 segments x 32 d-lanes
        double ssum = 0.0;
#pragma unroll
        for (int k = 0; k < 30; ++k) ssum += (double)ls[seg * 30 + k][dl];
        sbd[seg * 32 + dl] = ssum;
        __syncthreads();
        double off = 0.0;
        if (dir == 0) { for (int k = seg + 1; k < 8; ++k) off += sbd[k * 32 + dl]; }
        else          { for (int k = 0; k < seg; ++k)     off += sbd[k * 32 + dl]; }
        float* O = dir ? O2 : O1;
        const int d = dg * 32 + dl;
        double r = off;
        if (dir == 0) {                              // exclusive suffix of T1
#pragma unroll
            for (int k = 29; k >= 0; --k) {
                int c = seg * 30 + k;
                O[(h * NC + c) * Dd + d] = (float)r;
                r += (double)ls[c][dl];
            }
        } else {                                     // exclusive prefix of T2
#pragma unroll
            for (int k = 0; k < 30; ++k) {
                int c = seg * 30 + k;
                O[(h * NC + c) * Dd + d] = (float)r;
                r += (double)ls[c][dl];
            }
        }
        return;
    }
    // denominator scan for head h (sorted e arrays, coalesced load)
    const int h = blockIdx.x - NSCAN;
    float* l1 = smem;
    float* l2 = smem + NN;
    float* wsum = smem + 9600;
    for (int k = tid; k < NN; k += 256) { l1[k] = e1s[h * NN + k]; l2[k] = e2s[h * NN + k]; }
    __syncthreads();
    const int p0 = tid * 19;
    const int cnt = (p0 < NN) ? ((NN - p0 < 19) ? NN - p0 : 19) : 0;
    float sA = 0.f, sB = 0.f;
    for (int k = 0; k < cnt; ++k) { sA += l1[p0 + k]; sB += l2[p0 + k]; }
    float iA = sA, iB = sB;
    const int lane = tid & 63, w = tid >> 6;
#pragma unroll
    for (int d2 = 1; d2 < 64; d2 <<= 1) {
        float uA = __shfl_up(iA, d2), uB = __shfl_up(iB, d2);
        if (lane >= d2) { iA += uA; iB += uB; }
    }
    if (lane == 63) { wsum[w] = iA; wsum[4 + w] = iB; }
    __syncthreads();
    float baseA = 0.f, baseB = 0.f;
    for (int k = 0; k < w; ++k) { baseA += wsum[k]; baseB += wsum[4 + k]; }
    float TA = wsum[0] + wsum[1] + wsum[2] + wsum[3];
    float rA = baseA + iA - sA;    // exclusive prefix offsets
    float rB = baseB + iB - sB;
    for (int k = 0; k < cnt; ++k) {
        int p = p0 + k;
        DenS1[h * NN1 + p] = TA - rA;   // inclusive suffix of e1
        DenP2[h * NN1 + p] = rB;        // exclusive prefix of e2
        rA += l1[p]; rB += l2[p];
    }
    if (tid == 255) {
        DenS1[h * NN1 + NN] = 0.f;
        DenP2[h * NN1 + NN] = wsum[4] + wsum[5] + wsum[6] + wsum[7];
    }
}

// ---------- phC: emit Suf1 (incl suffix, e1) / Pre2 (excl prefix, e2) ----------
template <int Dd, int HD, int PACK>
__global__ __launch_bounds__(256) void phC(const float* __restrict__ hsrc, const int* __restrict__ inv,
                                           const float* __restrict__ e1s, const float* __restrict__ e2s,
                                           const float* __restrict__ O1, const float* __restrict__ O2,
                                           float* __restrict__ Suf1, float* __restrict__ Pre2) {
    __shared__ int inv_l[PACK * CL];
    __shared__ float w1s[PACK * CL], w2s[PACK * CL];
    const int h = blockIdx.y, tid = threadIdx.x;
    const int base = blockIdx.x * (PACK * CL);
    if (tid < PACK * CL) {
        inv_l[tid] = inv[h * NN + base + tid];
        w1s[tid] = e1s[h * NN + base + tid];
        w2s[tid] = e2s[h * NN + base + tid];
    }
    __syncthreads();
    const int sub = tid / Dd, d = tid % Dd;
    const int c = blockIdx.x * PACK + sub;
    float hv[CL];
#pragma unroll
    for (int p = 0; p < CL; ++p) {
        int j = inv_l[sub * CL + p];
        hv[p] = hsrc[(size_t)j * HD + h * Dd + d];
    }
    float r2 = O2[(h * NC + c) * Dd + d];
#pragma unroll
    for (int p = 0; p < CL; ++p) {
        int pp = c * CL + p;
        Pre2[((size_t)(h * NN1) + pp) * Dd + d] = r2;
        r2 += w2s[sub * CL + p] * hv[p];
    }
    if (c == NC - 1) {
        Pre2[((size_t)(h * NN1) + NN) * Dd + d] = r2;
        Suf1[((size_t)(h * NN1) + NN) * Dd + d] = 0.f;
    }
    float r1 = O1[(h * NC + c) * Dd + d];
#pragma unroll
    for (int p = CL - 1; p >= 0; --p) {
        int pp = c * CL + p;
        r1 += w1s[sub * CL + p] * hv[p];
        Suf1[((size_t)(h * NN1) + pp) * Dd + d] = r1;
    }
}

// ---------- kout1: combine + ELU -> h1abf; zero s2/t2. grid 900 ----------
__global__ __launch_bounds__(256) void kout1(const float* __restrict__ s1, const int* __restrict__ rks1,
                                             const float* __restrict__ Suf1, const float* __restrict__ Pre2,
                                             const float* __restrict__ DenS1, const float* __restrict__ DenP2,
                                             short* __restrict__ h1abf,
                                             float* __restrict__ s2, float* __restrict__ t2) {
    const int gtid = blockIdx.x * 256 + threadIdx.x;
    if (gtid < 3 * NN) { s2[gtid] = 0.f; t2[gtid] = 0.f; }
    for (int x = gtid; x < NN * 192; x += 900 * 256) {
        int i = x / 192, cc = x % 192, h = cc >> 6, d = cc & 63;
        float sv = s1[h * NN + i];
        float a = __expf(sv), b = __expf(0.2f * sv);
        int r = rks1[h * NN + i];
        size_t bp = ((size_t)(h * NN1) + r) * 64 + d;
        float num = a * Suf1[bp] + b * Pre2[bp];
        float den = a * DenS1[h * NN1 + r] + b * DenP2[h * NN1 + r];
        float v = num / den;
        v = v > 0.f ? v : (__expf(v) - 1.f);      // ELU
        h1abf[x] = bf16rne(v);
    }
}

// ---------- gemm1: h2 = h1a @ W2 + fused s2/t2 dots. grid (75,6) ----------
__global__ __launch_bounds__(256) void gemm1(const short* __restrict__ A, const short* __restrict__ W2T,
                                             const float* __restrict__ as2, const float* __restrict__ ad2,
                                             float* __restrict__ h2, float* __restrict__ s2,
                                             float* __restrict__ t2) {
    const int mb = blockIdx.x, nb = blockIdx.y, tid = threadIdx.x;
    const int lane = tid & 63, w = tid >> 6, q = lane >> 4, mr = lane & 15;
    const int m = mb * 64 + w * 16 + mr, n0 = nb * 64, hh = nb >> 1;
    f32x4 acc[4];
#pragma unroll
    for (int n = 0; n < 4; ++n) acc[n] = (f32x4){0.f, 0.f, 0.f, 0.f};
#pragma unroll
    for (int k0 = 0; k0 < 192; k0 += 32) {
        short8 af = *(const short8*)(A + (size_t)m * 192 + k0 + q * 8);
#pragma unroll
        for (int n = 0; n < 4; ++n) {
            short8 bf = *(const short8*)(W2T + (size_t)(n0 + n * 16 + mr) * 192 + k0 + q * 8);
            acc[n] = __builtin_amdgcn_mfma_f32_16x16x32_bf16(af, bf, acc[n], 0, 0, 0);
        }
    }
    float pse[4] = {0.f, 0.f, 0.f, 0.f}, pte[4] = {0.f, 0.f, 0.f, 0.f};
#pragma unroll
    for (int n = 0; n < 4; ++n) {
        int col = n0 + n * 16 + mr;
        float va = as2[col], vd = ad2[col];
#pragma unroll
        for (int r = 0; r < 4; ++r) {
            int row = mb * 64 + w * 16 + q * 4 + r;
            float v = acc[n][r];
            h2[(size_t)row * 384 + col] = v;
            pse[r] += v * va;
            pte[r] += v * vd;
        }
    }
#pragma unroll
    for (int off = 1; off < 16; off <<= 1) {
#pragma unroll
        for (int r = 0; r < 4; ++r) {
            pse[r] += __shfl_xor(pse[r], off);
            pte[r] += __shfl_xor(pte[r], off);
        }
    }
    if (mr == 0) {
#pragma unroll
        for (int r = 0; r < 4; ++r) {
            int row = mb * 64 + w * 16 + q * 4 + r;
            atomicAdd(&s2[hh * NN + row], pse[r]);
            atomicAdd(&t2[hh * NN + row], pte[r]);
        }
    }
}

// ---------- TAIL2: kout2 + F1 + F2 + mean pool. grid 300 (M=16) ----------
__global__ __launch_bounds__(256) void tail2(
    const float* __restrict__ s2, const int* __restrict__ rks2,
    const float* __restrict__ Suf1, const float* __restrict__ Pre2,
    const float* __restrict__ DenS1, const float* __restrict__ DenP2,
    const float* __restrict__ flat, const short* __restrict__ P1T, const short* __restrict__ P2T,
    const float* __restrict__ b1, const float* __restrict__ b2,
    float* __restrict__ out) {
    __shared__ short g[16][168];
    __shared__ short f1[16][136];
    const int mb = blockIdx.x, tid = threadIdx.x;
    for (int e = tid; e < 16 * 160; e += 256) {   // build g tile
        int row = e / 160, c = e % 160;
        int i = mb * 16 + row;
        float v;
        if (c < 128) {
            float acc = 0.f;
#pragma unroll
            for (int h = 0; h < 3; ++h) {
                float sv = s2[h * NN + i];
                float a = __expf(sv), b = __expf(0.2f * sv);
                int r = rks2[h * NN + i];
                size_t bp = ((size_t)(h * NN1) + r) * 128 + c;
                float num = a * Suf1[bp] + b * Pre2[bp];
                float den = a * DenS1[h * NN1 + r] + b * DenP2[h * NN1 + r];
                acc += num / den;
            }
            v = acc * (1.f / 3.f);
        } else if (c < 143) v = flat[i * 15 + (c - 128)];
        else v = 0.f;
        g[row][c] = bf16rne(v);
    }
    __syncthreads();
    const int lane = tid & 63, w = tid >> 6, q = lane >> 4, mr = lane & 15;
    // GEMM1: M=16, N=128, K=160; wave w handles cols w*32..w*32+31
    f32x4 a1[2];
#pragma unroll
    for (int n = 0; n < 2; ++n) a1[n] = (f32x4){0.f, 0.f, 0.f, 0.f};
#pragma unroll
    for (int k0 = 0; k0 < 160; k0 += 32) {
        short8 af = *(const short8*)&g[mr][k0 + q * 8];
#pragma unroll
        for (int n = 0; n < 2; ++n) {
            short8 bf = *(const short8*)(P1T + (size_t)(w * 32 + n * 16 + mr) * 160 + k0 + q * 8);
            a1[n] = __builtin_amdgcn_mfma_f32_16x16x32_bf16(af, bf, a1[n], 0, 0, 0);
        }
    }
#pragma unroll
    for (int n = 0; n < 2; ++n) {
        int col = w * 32 + n * 16 + mr;
        float bv = b1[col];
#pragma unroll
        for (int r = 0; r < 4; ++r) {
            int row = q * 4 + r;
            f1[row][col] = bf16rne(fmaxf(a1[n][r] + bv, 0.f));
        }
    }
    __syncthreads();
    // GEMM2: M=16, N=64, K=128; wave w handles cols w*16..w*16+15
    f32x4 a2 = (f32x4){0.f, 0.f, 0.f, 0.f};
#pragma unroll
    for (int k0 = 0; k0 < 128; k0 += 32) {
        short8 af = *(const short8*)&f1[mr][k0 + q * 8];
        short8 bf = *(const short8*)(P2T + (size_t)(w * 16 + mr) * 128 + k0 + q * 8);
        a2 = __builtin_amdgcn_mfma_f32_16x16x32_bf16(af, bf, a2, 0, 0, 0);
    }
    float* f2f = (float*)&g[0][0];                 // reuse g LDS: 16*65*4 = 4160 B
    {
        int col = w * 16 + mr;
        float bv = b2[col];
#pragma unroll
        for (int r = 0; r < 4; ++r) {
            int row = q * 4 + r;
            f2f[row * 65 + col] = fmaxf(a2[r] + bv, 0.f);
        }
    }
    __syncthreads();
    if (tid < 64) {                                // mean pool (atomics into zeroed out)
        int d = tid;
        int b0 = (mb * 16) / 150;
        int bend = (mb * 16 + 15) / 150;
        float sa = 0.f, sb = 0.f;
        for (int row = 0; row < 16; ++row) {
            float v = f2f[row * 65 + d];
            int b = (mb * 16 + row) / 150;
            if (b == b0) sa += v; else sb += v;
        }
        atomicAdd(&out[b0 * 64 + d], sa * (1.f / 150.f));
        if (bend != b0) atomicAdd(&out[bend * 64 + d], sb * (1.f / 150.f));
    }
}

extern "C" void kernel_launch(void* const* d_in, const int* in_sizes, int n_in,
                              void* d_out, int out_size, void* d_ws, size_t ws_size,
                              hipStream_t stream) {
    const float* flat   = (const float*)d_in[0];
    const float* amask  = (const float*)d_in[1];
    const float* W1     = (const float*)d_in[2];
    const float* a_src1 = (const float*)d_in[3];
    const float* a_dst1 = (const float*)d_in[4];
    const float* W2     = (const float*)d_in[5];
    const float* a_src2 = (const float*)d_in[6];
    const float* a_dst2 = (const float*)d_in[7];
    const float* P1     = (const float*)d_in[8];
    const float* b1     = (const float*)d_in[9];
    const float* P2     = (const float*)d_in[10];
    const float* b2     = (const float*)d_in[11];
    float* out = (float*)d_out;

    char* wsb = (char*)d_ws;
    ull*   sortedK = (ull*)  (wsb + 0);         // 3*8*600*8 = 115200 (replaces partial)
    float* s1      = (float*)(wsb + 921600);    // 57600
    float* t1      = (float*)(wsb + 979200);
    float* s2      = (float*)(wsb + 1036800);
    float* t2      = (float*)(wsb + 1094400);
    int*   rks1    = (int*)  (wsb + 1152000);   // 57600
    int*   rks2    = (int*)  (wsb + 1209600);
    float* h1      = (float*)(wsb + 1267200);   // 3686400
    int*   inv     = (int*)  (wsb + 4953600);   // 57600
    float* e1s     = (float*)(wsb + 5011200);
    float* e2s     = (float*)(wsb + 5068800);
    float* DenS1   = (float*)(wsb + 5126400);   // 57664
    float* DenP2   = (float*)(wsb + 5184064);   // 57664
    float* Tot1    = (float*)(wsb + 5241728);   // 368640
    float* Tot2    = (float*)(wsb + 5610368);
    float* Off1    = (float*)(wsb + 5979008);
    float* Off2    = (float*)(wsb + 6347648);
    float* Suf1    = (float*)(wsb + 6716288);   // 7374336
    float* Pre2    = (float*)(wsb + 14090624);  // 7374336
    float* h2      = (float*)(wsb + 21464960);  // 7372800
    short* h1abf   = (short*)(wsb + 28837760);  // 1843200
    short* W2T     = (short*)(wsb + 30680960);  // 147456
    short* P1T     = (short*)(wsb + 30828416);  // 40960
    short* P2T     = (short*)(wsb + 30869376);  // 16384 -> end 30885760

    prep<<<1200, 256, 0, stream>>>(flat, amask, W1, a_src1, a_dst1, W2, P1, P2,
                                   h1, s1, t1, W2T, P1T, P2T, out);
    // layer 1 (Dd=64, HD=192, PACK=4)
    sortk<<<dim3(8, 3), 256, 0, stream>>>(t1, sortedK);
    kranksc<<<dim3(38, 3), 256, 0, stream>>>(s1, t1, sortedK, inv, e1s, e2s, rks1);
    phA<64, 192, 4><<<dim3(60, 3), 256, 0, stream>>>(h1, inv, e1s, e2s, Tot1, Tot2);
    phBden<64><<<15, 256, 0, stream>>>(Tot1, Tot2, e1s, e2s, Off1, Off2, DenS1, DenP2);
    phC<64, 192, 4><<<dim3(60, 3), 256, 0, stream>>>(h1, inv, e1s, e2s, Off1, Off2, Suf1, Pre2);
    kout1<<<900, 256, 0, stream>>>(s1, rks1, Suf1, Pre2, DenS1, DenP2, h1abf, s2, t2);
    gemm1<<<dim3(75, 6), 256, 0, stream>>>(h1abf, W2T, a_src2, a_dst2, h2, s2, t2);
    // layer 2 (Dd=128, HD=384, PACK=2)
    sortk<<<dim3(8, 3), 256, 0, stream>>>(t2, sortedK);
    kranksc<<<dim3(38, 3), 256, 0, stream>>>(s2, t2, sortedK, inv, e1s, e2s, rks2);
    phA<128, 384, 2><<<dim3(120, 3), 256, 0, stream>>>(h2, inv, e1s, e2s, Tot1, Tot2);
    phBden<128><<<27, 256, 0, stream>>>(Tot1, Tot2, e1s, e2s, Off1, Off2, DenS1, DenP2);
    phC<128, 384, 2><<<dim3(120, 3), 256, 0, stream>>>(h2, inv, e1s, e2s, Off1, Off2, Suf1, Pre2);
    tail2<<<300, 256, 0, stream>>>(s2, rks2, Suf1, Pre2, DenS1, DenP2, flat, P1T, P2T, b1, b2, out);
}

// Round 7
// 193.727 us; speedup vs baseline: 1.2039x; 1.2039x over previous
//
#include <hip/hip_runtime.h>

typedef __attribute__((ext_vector_type(8))) short short8;
typedef __attribute__((ext_vector_type(4))) float f32x4;
typedef unsigned long long ull;

#define NN 4800
#define NN1 4801
#define NC 240
#define CL 20
#define KLEN 600

__device__ __forceinline__ short bf16rne(float x) {
    unsigned u = __float_as_uint(x);
    u = (u + 0x7FFFu + ((u >> 16) & 1u)) >> 16;
    return (short)u;
}
// monotonic float->uint key (ascending float == ascending uint)
__device__ __forceinline__ unsigned fkey(float f) {
    unsigned i = __float_as_uint(f);
    return (i & 0x80000000u) ? ~i : (i | 0x80000000u);
}

// ---------- prep: h1 (fused s1/t1 dots), weight transposes, mask copy, out zero, acc zero ----------
__global__ __launch_bounds__(256) void prep(
    const float* __restrict__ flat, const float* __restrict__ amask,
    const float* __restrict__ W1, const float* __restrict__ as1, const float* __restrict__ ad1,
    const float* __restrict__ W2, const float* __restrict__ P1, const float* __restrict__ P2,
    float* __restrict__ h1, float* __restrict__ s1, float* __restrict__ t1,
    short* __restrict__ W2T, short* __restrict__ P1T, short* __restrict__ P2T,
    float* __restrict__ out, int* __restrict__ acc) {
    const int gtid = blockIdx.x * 256 + threadIdx.x;
    const int GT = 1200 * 256;
    for (int x = gtid; x < 138080; x += GT) {
        if (x < 73728) {                       // W2T [384][192]
            int n = x / 192, k = x % 192;
            W2T[x] = bf16rne(W2[k * 384 + n]);
        } else if (x < 94208) {                // P1T [128][160] (zero-padded K)
            int z = x - 73728; int n = z / 160, k = z % 160;
            P1T[z] = bf16rne(k < 143 ? P1[k * 128 + n] : 0.f);
        } else if (x < 102400) {               // P2T [64][128]
            int z = x - 94208; int n = z / 128, k = z % 128;
            P2T[z] = bf16rne(P2[k * 64 + n]);
        } else if (x < 107232) {               // mask passthrough (4832)
            int m = x - 102400;
            out[2048 + m] = amask[m];
        } else if (x < 109280) {
            out[x - 107232] = 0.f;             // pool accumulators (2048)
        } else {
            acc[x - 109280] = 0;               // packed rank counters for layer-1 krks (28800)
        }
    }
    const int lane = threadIdx.x & 63;
    const int gw = (gtid >> 6);
    for (int task = gw; task < 3 * NN; task += (GT >> 6)) {
        int h = task / NN, i = task % NN;
        int col = h * 64 + lane;
        const float* fr = flat + i * 15;
        float hv = 0.f;
#pragma unroll
        for (int f = 0; f < 15; ++f) hv += fr[f] * W1[f * 192 + col];
        h1[i * 192 + col] = hv;                // single h1 pass
        float ps = hv * as1[col], pt = hv * ad1[col];
#pragma unroll
        for (int off = 32; off; off >>= 1) { ps += __shfl_xor(ps, off); pt += __shfl_xor(pt, off); }
        if (lane == 0) { s1[h * NN + i] = ps; t1[h * NN + i] = pt; }
    }
}

// ---------- krks: fused rank-count + 8th-arriver scatter (R3/R4 A/B: beats split by ~3us). grid (38,3,8) ----------
// acc[h][q] packed: bits 0..23 = running rank sum, bits 24+ = arrival count.
__global__ __launch_bounds__(256) void krks(const float* __restrict__ s, const float* __restrict__ t,
                                            int* __restrict__ acc, int* __restrict__ inv,
                                            float* __restrict__ e1s, float* __restrict__ e2s,
                                            int* __restrict__ rks) {
    __shared__ __align__(16) ull ts[KLEN];
    const int h = blockIdx.y, kc = blockIdx.z;
    const float* tp = t + h * NN + kc * KLEN;
    for (int k = threadIdx.x; k < KLEN; k += 256)
        ts[k] = ((ull)fkey(tp[k]) << 32) | (unsigned)k;
    __syncthreads();
    int q = blockIdx.x * 256 + threadIdx.x;
    if (q >= 2 * NN) return;
    ull uq;
    if (q < NN) {
        int tb = q - kc * KLEN;
        int tbc = tb < 0 ? 0 : (tb > KLEN ? KLEN : tb);
        uq = ((ull)fkey(t[h * NN + q]) << 32) | (unsigned)tbc;
    } else {
        uq = ((ull)fkey(-s[h * NN + q - NN]) << 32) | (unsigned)KLEN;
    }
    int cnt = 0;
#pragma unroll 4
    for (int k = 0; k < KLEN; k += 2) {
        ulonglong2 v = *(const ulonglong2*)&ts[k];   // wave-uniform LDS broadcast
        cnt += (v.x < uq);
        cnt += (v.y < uq);
    }
    unsigned ret = atomicAdd((unsigned*)&acc[h * 2 * NN + q], (unsigned)cnt | (1u << 24));
    if ((ret >> 24) == 7u) {                          // 8th arrival: rank complete
        int sum = (int)((ret & 0xFFFFFFu) + (unsigned)cnt);
        if (q < NN) {
            float tv = t[h * NN + q];
            inv[h * NN + sum] = q;
            e1s[h * NN + sum] = __expf(tv);
            e2s[h * NN + sum] = __expf(0.2f * tv);
        } else {
            rks[h * NN + q - NN] = sum;
        }
    }
}

// ---------- phAden: chunk totals (bx < NB) + denominator scans (bx == NB). grid (NB+1, 3) ----------
template <int Dd, int HD, int PACK>
__global__ __launch_bounds__(256) void phAden(const float* __restrict__ hsrc, const int* __restrict__ inv,
                                              const float* __restrict__ e1s, const float* __restrict__ e2s,
                                              float* __restrict__ T1, float* __restrict__ T2,
                                              float* __restrict__ DenS1, float* __restrict__ DenP2) {
    constexpr int NB = NC / PACK;
    __shared__ int inv_l[PACK * CL];
    __shared__ float w1s[PACK * CL], w2s[PACK * CL];
    __shared__ float wsum[8];
    const int h = blockIdx.y, tid = threadIdx.x;
    if (blockIdx.x == NB) {
        // denominator scan for head h (sorted e arrays, L2-resident direct reads)
        const float* l1 = e1s + h * NN;
        const float* l2 = e2s + h * NN;
        const int p0 = tid * 19;
        const int cnt = (p0 < NN) ? ((NN - p0 < 19) ? NN - p0 : 19) : 0;
        float sA = 0.f, sB = 0.f;
        for (int k = 0; k < cnt; ++k) { sA += l1[p0 + k]; sB += l2[p0 + k]; }
        float iA = sA, iB = sB;
        const int lane = tid & 63, w = tid >> 6;
#pragma unroll
        for (int d2 = 1; d2 < 64; d2 <<= 1) {
            float uA = __shfl_up(iA, d2), uB = __shfl_up(iB, d2);
            if (lane >= d2) { iA += uA; iB += uB; }
        }
        if (lane == 63) { wsum[w] = iA; wsum[4 + w] = iB; }
        __syncthreads();
        float baseA = 0.f, baseB = 0.f;
        for (int k = 0; k < w; ++k) { baseA += wsum[k]; baseB += wsum[4 + k]; }
        float TA = wsum[0] + wsum[1] + wsum[2] + wsum[3];
        float rA = baseA + iA - sA;    // exclusive prefix offsets
        float rB = baseB + iB - sB;
        for (int k = 0; k < cnt; ++k) {
            int p = p0 + k;
            DenS1[h * NN1 + p] = TA - rA;   // inclusive suffix of e1
            DenP2[h * NN1 + p] = rB;        // exclusive prefix of e2
            rA += l1[p]; rB += l2[p];
        }
        if (tid == 255) {
            DenS1[h * NN1 + NN] = 0.f;
            DenP2[h * NN1 + NN] = wsum[4] + wsum[5] + wsum[6] + wsum[7];
        }
        return;
    }
    const int cb = blockIdx.x;
    const int base = cb * (PACK * CL);
    if (tid < PACK * CL) {
        inv_l[tid] = inv[h * NN + base + tid];
        w1s[tid] = e1s[h * NN + base + tid];
        w2s[tid] = e2s[h * NN + base + tid];
    }
    __syncthreads();
    const int sub = tid / Dd, d = tid % Dd;
    const int c = cb * PACK + sub;
    float a1 = 0.f, a2 = 0.f;
#pragma unroll
    for (int p = 0; p < CL; ++p) {
        int j = inv_l[sub * CL + p];
        float hv = hsrc[(size_t)j * HD + h * Dd + d];
        a1 += w1s[sub * CL + p] * hv;
        a2 += w2s[sub * CL + p] * hv;
    }
    T1[(h * NC + c) * Dd + d] = a1;
    T2[(h * NC + c) * Dd + d] = a2;
}

// ---------- phBscan: PARALLEL Tot scans only (segmented, 8x30). grid 6*G ----------
template <int Dd>
__global__ __launch_bounds__(256) void phBscan(const float* __restrict__ T1, const float* __restrict__ T2,
                                               float* __restrict__ O1, float* __restrict__ O2) {
    __shared__ __align__(16) float smem[8192];       // ls 7680 floats + sbd 512 floats(=256 dbl)
    const int tid = threadIdx.x;
    float (*ls)[32] = (float(*)[32])smem;            // [240][32]
    double* sbd = (double*)(smem + 7680);            // [8][32] segment sums
    const int b = blockIdx.x;
    const int h = b % 3, rest = b / 3, dir = rest & 1, dg = rest >> 1;
    const float* T = dir ? T2 : T1;
    for (int idx = tid; idx < NC * 32; idx += 256) {
        int c = idx >> 5, dl = idx & 31;
        ls[c][dl] = T[(h * NC + c) * Dd + dg * 32 + dl];
    }
    __syncthreads();
    const int seg = tid >> 5, dl = tid & 31;         // 8 segments x 32 d-lanes
    double ssum = 0.0;
#pragma unroll
    for (int k = 0; k < 30; ++k) ssum += (double)ls[seg * 30 + k][dl];
    sbd[seg * 32 + dl] = ssum;
    __syncthreads();
    double off = 0.0;
    if (dir == 0) { for (int k = seg + 1; k < 8; ++k) off += sbd[k * 32 + dl]; }
    else          { for (int k = 0; k < seg; ++k)     off += sbd[k * 32 + dl]; }
    float* O = dir ? O2 : O1;
    const int d = dg * 32 + dl;
    double r = off;
    if (dir == 0) {                                  // exclusive suffix of T1
#pragma unroll
        for (int k = 29; k >= 0; --k) {
            int c = seg * 30 + k;
            O[(h * NC + c) * Dd + d] = (float)r;
            r += (double)ls[c][dl];
        }
    } else {                                         // exclusive prefix of T2
#pragma unroll
        for (int k = 0; k < 30; ++k) {
            int c = seg * 30 + k;
            O[(h * NC + c) * Dd + d] = (float)r;
            r += (double)ls[c][dl];
        }
    }
}

// ---------- phC: emit Suf1 (incl suffix, e1) / Pre2 (excl prefix, e2) ----------
template <int Dd, int HD, int PACK>
__global__ __launch_bounds__(256) void phC(const float* __restrict__ hsrc, const int* __restrict__ inv,
                                           const float* __restrict__ e1s, const float* __restrict__ e2s,
                                           const float* __restrict__ O1, const float* __restrict__ O2,
                                           float* __restrict__ Suf1, float* __restrict__ Pre2) {
    __shared__ int inv_l[PACK * CL];
    __shared__ float w1s[PACK * CL], w2s[PACK * CL];
    const int h = blockIdx.y, tid = threadIdx.x;
    const int base = blockIdx.x * (PACK * CL);
    if (tid < PACK * CL) {
        inv_l[tid] = inv[h * NN + base + tid];
        w1s[tid] = e1s[h * NN + base + tid];
        w2s[tid] = e2s[h * NN + base + tid];
    }
    __syncthreads();
    const int sub = tid / Dd, d = tid % Dd;
    const int c = blockIdx.x * PACK + sub;
    float hv[CL];
#pragma unroll
    for (int p = 0; p < CL; ++p) {
        int j = inv_l[sub * CL + p];
        hv[p] = hsrc[(size_t)j * HD + h * Dd + d];
    }
    float r2 = O2[(h * NC + c) * Dd + d];
#pragma unroll
    for (int p = 0; p < CL; ++p) {
        int pp = c * CL + p;
        Pre2[((size_t)(h * NN1) + pp) * Dd + d] = r2;
        r2 += w2s[sub * CL + p] * hv[p];
    }
    if (c == NC - 1) {
        Pre2[((size_t)(h * NN1) + NN) * Dd + d] = r2;
        Suf1[((size_t)(h * NN1) + NN) * Dd + d] = 0.f;
    }
    float r1 = O1[(h * NC + c) * Dd + d];
#pragma unroll
    for (int p = CL - 1; p >= 0; --p) {
        int pp = c * CL + p;
        r1 += w1s[sub * CL + p] * hv[p];
        Suf1[((size_t)(h * NN1) + pp) * Dd + d] = r1;
    }
}

// ---------- kout1: combine + ELU -> h1abf; zero s2/t2 + acc (layer-2 krks). grid 900 ----------
__global__ __launch_bounds__(256) void kout1(const float* __restrict__ s1, const int* __restrict__ rks1,
                                             const float* __restrict__ Suf1, const float* __restrict__ Pre2,
                                             const float* __restrict__ DenS1, const float* __restrict__ DenP2,
                                             short* __restrict__ h1abf,
                                             float* __restrict__ s2, float* __restrict__ t2,
                                             int* __restrict__ acc) {
    const int gtid = blockIdx.x * 256 + threadIdx.x;
    if (gtid < 3 * NN) { s2[gtid] = 0.f; t2[gtid] = 0.f; }
    if (gtid < 3 * 2 * NN) acc[gtid] = 0;
    for (int x = gtid; x < NN * 192; x += 900 * 256) {
        int i = x / 192, cc = x % 192, h = cc >> 6, d = cc & 63;
        float sv = s1[h * NN + i];
        float a = __expf(sv), b = __expf(0.2f * sv);
        int r = rks1[h * NN + i];
        size_t bp = ((size_t)(h * NN1) + r) * 64 + d;
        float num = a * Suf1[bp] + b * Pre2[bp];
        float den = a * DenS1[h * NN1 + r] + b * DenP2[h * NN1 + r];
        float v = num / den;
        v = v > 0.f ? v : (__expf(v) - 1.f);      // ELU
        h1abf[x] = bf16rne(v);
    }
}

// ---------- gemm1: h2 = h1a @ W2 + fused s2/t2 dots. grid (75,6) ----------
__global__ __launch_bounds__(256) void gemm1(const short* __restrict__ A, const short* __restrict__ W2T,
                                             const float* __restrict__ as2, const float* __restrict__ ad2,
                                             float* __restrict__ h2, float* __restrict__ s2,
                                             float* __restrict__ t2) {
    const int mb = blockIdx.x, nb = blockIdx.y, tid = threadIdx.x;
    const int lane = tid & 63, w = tid >> 6, q = lane >> 4, mr = lane & 15;
    const int m = mb * 64 + w * 16 + mr, n0 = nb * 64, hh = nb >> 1;
    f32x4 acc[4];
#pragma unroll
    for (int n = 0; n < 4; ++n) acc[n] = (f32x4){0.f, 0.f, 0.f, 0.f};
#pragma unroll
    for (int k0 = 0; k0 < 192; k0 += 32) {
        short8 af = *(const short8*)(A + (size_t)m * 192 + k0 + q * 8);
#pragma unroll
        for (int n = 0; n < 4; ++n) {
            short8 bf = *(const short8*)(W2T + (size_t)(n0 + n * 16 + mr) * 192 + k0 + q * 8);
            acc[n] = __builtin_amdgcn_mfma_f32_16x16x32_bf16(af, bf, acc[n], 0, 0, 0);
        }
    }
    float pse[4] = {0.f, 0.f, 0.f, 0.f}, pte[4] = {0.f, 0.f, 0.f, 0.f};
#pragma unroll
    for (int n = 0; n < 4; ++n) {
        int col = n0 + n * 16 + mr;
        float va = as2[col], vd = ad2[col];
#pragma unroll
        for (int r = 0; r < 4; ++r) {
            int row = mb * 64 + w * 16 + q * 4 + r;
            float v = acc[n][r];
            h2[(size_t)row * 384 + col] = v;
            pse[r] += v * va;
            pte[r] += v * vd;
        }
    }
#pragma unroll
    for (int off = 1; off < 16; off <<= 1) {
#pragma unroll
        for (int r = 0; r < 4; ++r) {
            pse[r] += __shfl_xor(pse[r], off);
            pte[r] += __shfl_xor(pte[r], off);
        }
    }
    if (mr == 0) {
#pragma unroll
        for (int r = 0; r < 4; ++r) {
            int row = mb * 64 + w * 16 + q * 4 + r;
            atomicAdd(&s2[hh * NN + row], pse[r]);
            atomicAdd(&t2[hh * NN + row], pte[r]);
        }
    }
}

// ---------- TAIL2: kout2 + F1 + F2 + mean pool. grid 300 (M=16) ----------
__global__ __launch_bounds__(256) void tail2(
    const float* __restrict__ s2, const int* __restrict__ rks2,
    const float* __restrict__ Suf1, const float* __restrict__ Pre2,
    const float* __restrict__ DenS1, const float* __restrict__ DenP2,
    const float* __restrict__ flat, const short* __restrict__ P1T, const short* __restrict__ P2T,
    const float* __restrict__ b1, const float* __restrict__ b2,
    float* __restrict__ out) {
    __shared__ short g[16][168];
    __shared__ short f1[16][136];
    const int mb = blockIdx.x, tid = threadIdx.x;
    for (int e = tid; e < 16 * 160; e += 256) {   // build g tile
        int row = e / 160, c = e % 160;
        int i = mb * 16 + row;
        float v;
        if (c < 128) {
            float acc = 0.f;
#pragma unroll
            for (int h = 0; h < 3; ++h) {
                float sv = s2[h * NN + i];
                float a = __expf(sv), b = __expf(0.2f * sv);
                int r = rks2[h * NN + i];
                size_t bp = ((size_t)(h * NN1) + r) * 128 + c;
                float num = a * Suf1[bp] + b * Pre2[bp];
                float den = a * DenS1[h * NN1 + r] + b * DenP2[h * NN1 + r];
                acc += num / den;
            }
            v = acc * (1.f / 3.f);
        } else if (c < 143) v = flat[i * 15 + (c - 128)];
        else v = 0.f;
        g[row][c] = bf16rne(v);
    }
    __syncthreads();
    const int lane = tid & 63, w = tid >> 6, q = lane >> 4, mr = lane & 15;
    // GEMM1: M=16, N=128, K=160; wave w handles cols w*32..w*32+31
    f32x4 a1[2];
#pragma unroll
    for (int n = 0; n < 2; ++n) a1[n] = (f32x4){0.f, 0.f, 0.f, 0.f};
#pragma unroll
    for (int k0 = 0; k0 < 160; k0 += 32) {
        short8 af = *(const short8*)&g[mr][k0 + q * 8];
#pragma unroll
        for (int n = 0; n < 2; ++n) {
            short8 bf = *(const short8*)(P1T + (size_t)(w * 32 + n * 16 + mr) * 160 + k0 + q * 8);
            a1[n] = __builtin_amdgcn_mfma_f32_16x16x32_bf16(af, bf, a1[n], 0, 0, 0);
        }
    }
#pragma unroll
    for (int n = 0; n < 2; ++n) {
        int col = w * 32 + n * 16 + mr;
        float bv = b1[col];
#pragma unroll
        for (int r = 0; r < 4; ++r) {
            int row = q * 4 + r;
            f1[row][col] = bf16rne(fmaxf(a1[n][r] + bv, 0.f));
        }
    }
    __syncthreads();
    // GEMM2: M=16, N=64, K=128; wave w handles cols w*16..w*16+15
    f32x4 a2 = (f32x4){0.f, 0.f, 0.f, 0.f};
#pragma unroll
    for (int k0 = 0; k0 < 128; k0 += 32) {
        short8 af = *(const short8*)&f1[mr][k0 + q * 8];
        short8 bf = *(const short8*)(P2T + (size_t)(w * 16 + mr) * 128 + k0 + q * 8);
        a2 = __builtin_amdgcn_mfma_f32_16x16x32_bf16(af, bf, a2, 0, 0, 0);
    }
    float* f2f = (float*)&g[0][0];                 // reuse g LDS: 16*65*4 = 4160 B
    {
        int col = w * 16 + mr;
        float bv = b2[col];
#pragma unroll
        for (int r = 0; r < 4; ++r) {
            int row = q * 4 + r;
            f2f[row * 65 + col] = fmaxf(a2[r] + bv, 0.f);
        }
    }
    __syncthreads();
    if (tid < 64) {                                // mean pool (atomics into zeroed out)
        int d = tid;
        int b0 = (mb * 16) / 150;
        int bend = (mb * 16 + 15) / 150;
        float sa = 0.f, sb = 0.f;
        for (int row = 0; row < 16; ++row) {
            float v = f2f[row * 65 + d];
            int b = (mb * 16 + row) / 150;
            if (b == b0) sa += v; else sb += v;
        }
        atomicAdd(&out[b0 * 64 + d], sa * (1.f / 150.f));
        if (bend != b0) atomicAdd(&out[bend * 64 + d], sb * (1.f / 150.f));
    }
}

extern "C" void kernel_launch(void* const* d_in, const int* in_sizes, int n_in,
                              void* d_out, int out_size, void* d_ws, size_t ws_size,
                              hipStream_t stream) {
    const float* flat   = (const float*)d_in[0];
    const float* amask  = (const float*)d_in[1];
    const float* W1     = (const float*)d_in[2];
    const float* a_src1 = (const float*)d_in[3];
    const float* a_dst1 = (const float*)d_in[4];
    const float* W2     = (const float*)d_in[5];
    const float* a_src2 = (const float*)d_in[6];
    const float* a_dst2 = (const float*)d_in[7];
    const float* P1     = (const float*)d_in[8];
    const float* b1     = (const float*)d_in[9];
    const float* P2     = (const float*)d_in[10];
    const float* b2     = (const float*)d_in[11];
    float* out = (float*)d_out;

    char* wsb = (char*)d_ws;
    int*   acc     = (int*)  (wsb + 0);         // 3*9600*4 = 115200 (packed rank counters)
    float* s1      = (float*)(wsb + 921600);    // 57600
    float* t1      = (float*)(wsb + 979200);
    float* s2      = (float*)(wsb + 1036800);
    float* t2      = (float*)(wsb + 1094400);
    int*   rks1    = (int*)  (wsb + 1152000);   // 57600
    int*   rks2    = (int*)  (wsb + 1209600);
    float* h1      = (float*)(wsb + 1267200);   // 3686400
    int*   inv     = (int*)  (wsb + 4953600);   // 57600
    float* e1s     = (float*)(wsb + 5011200);
    float* e2s     = (float*)(wsb + 5068800);
    float* DenS1   = (float*)(wsb + 5126400);   // 57664
    float* DenP2   = (float*)(wsb + 5184064);   // 57664
    float* Tot1    = (float*)(wsb + 5241728);   // 368640
    float* Tot2    = (float*)(wsb + 5610368);
    float* Off1    = (float*)(wsb + 5979008);
    float* Off2    = (float*)(wsb + 6347648);
    float* Suf1    = (float*)(wsb + 6716288);   // 7374336
    float* Pre2    = (float*)(wsb + 14090624);  // 7374336
    float* h2      = (float*)(wsb + 21464960);  // 7372800
    short* h1abf   = (short*)(wsb + 28837760);  // 1843200
    short* W2T     = (short*)(wsb + 30680960);  // 147456
    short* P1T     = (short*)(wsb + 30828416);  // 40960
    short* P2T     = (short*)(wsb + 30869376);  // 16384 -> end 30885760

    prep<<<1200, 256, 0, stream>>>(flat, amask, W1, a_src1, a_dst1, W2, P1, P2,
                                   h1, s1, t1, W2T, P1T, P2T, out, acc);
    // layer 1 (Dd=64, HD=192, PACK=4)
    krks<<<dim3(38, 3, 8), 256, 0, stream>>>(s1, t1, acc, inv, e1s, e2s, rks1);
    phAden<64, 192, 4><<<dim3(61, 3), 256, 0, stream>>>(h1, inv, e1s, e2s, Tot1, Tot2, DenS1, DenP2);
    phBscan<64><<<12, 256, 0, stream>>>(Tot1, Tot2, Off1, Off2);
    phC<64, 192, 4><<<dim3(60, 3), 256, 0, stream>>>(h1, inv, e1s, e2s, Off1, Off2, Suf1, Pre2);
    kout1<<<900, 256, 0, stream>>>(s1, rks1, Suf1, Pre2, DenS1, DenP2, h1abf, s2, t2, acc);
    gemm1<<<dim3(75, 6), 256, 0, stream>>>(h1abf, W2T, a_src2, a_dst2, h2, s2, t2);
    // layer 2 (Dd=128, HD=384, PACK=2)
    krks<<<dim3(38, 3, 8), 256, 0, stream>>>(s2, t2, acc, inv, e1s, e2s, rks2);
    phAden<128, 384, 2><<<dim3(121, 3), 256, 0, stream>>>(h2, inv, e1s, e2s, Tot1, Tot2, DenS1, DenP2);
    phBscan<128><<<24, 256, 0, stream>>>(Tot1, Tot2, Off1, Off2);
    phC<128, 384, 2><<<dim3(120, 3), 256, 0, stream>>>(h2, inv, e1s, e2s, Off1, Off2, Suf1, Pre2);
    tail2<<<300, 256, 0, stream>>>(s2, rks2, Suf1, Pre2, DenS1, DenP2, flat, P1T, P2T, b1, b2, out);
}

// Round 8
// 180.643 us; speedup vs baseline: 1.2911x; 1.0724x over previous
//
#include <hip/hip_runtime.h>

typedef __attribute__((ext_vector_type(8))) short short8;
typedef __attribute__((ext_vector_type(4))) float f32x4;
typedef unsigned long long ull;

#define NN 4800
#define NN1 4801
#define NC 240
#define CL 20
#define KLEN 600

__device__ __forceinline__ short bf16rne(float x) {
    unsigned u = __float_as_uint(x);
    u = (u + 0x7FFFu + ((u >> 16) & 1u)) >> 16;
    return (short)u;
}
// monotonic float->uint key (ascending float == ascending uint)
__device__ __forceinline__ unsigned fkey(float f) {
    unsigned i = __float_as_uint(f);
    return (i & 0x80000000u) ? ~i : (i | 0x80000000u);
}

// ---------- prep: h1 (single pass, fused with s1/t1 dots), weight transposes, mask copy, out zero ----------
__global__ __launch_bounds__(256) void prep(
    const float* __restrict__ flat, const float* __restrict__ amask,
    const float* __restrict__ W1, const float* __restrict__ as1, const float* __restrict__ ad1,
    const float* __restrict__ W2, const float* __restrict__ P1, const float* __restrict__ P2,
    float* __restrict__ h1, float* __restrict__ s1, float* __restrict__ t1,
    short* __restrict__ W2T, short* __restrict__ P1T, short* __restrict__ P2T,
    float* __restrict__ out) {
    const int gtid = blockIdx.x * 256 + threadIdx.x;
    const int GT = 1200 * 256;
    for (int x = gtid; x < 109280; x += GT) {
        if (x < 73728) {                       // W2T [384][192]
            int n = x / 192, k = x % 192;
            W2T[x] = bf16rne(W2[k * 384 + n]);
        } else if (x < 94208) {                // P1T [128][160] (zero-padded K)
            int z = x - 73728; int n = z / 160, k = z % 160;
            P1T[z] = bf16rne(k < 143 ? P1[k * 128 + n] : 0.f);
        } else if (x < 102400) {               // P2T [64][128]
            int z = x - 94208; int n = z / 128, k = z % 128;
            P2T[z] = bf16rne(P2[k * 64 + n]);
        } else if (x < 107232) {               // mask passthrough (4832)
            int m = x - 102400;
            out[2048 + m] = amask[m];
        } else {
            out[x - 107232] = 0.f;             // pool accumulators (2048)
        }
    }
    const int lane = threadIdx.x & 63;
    const int gw = (gtid >> 6);
    for (int task = gw; task < 3 * NN; task += (GT >> 6)) {
        int h = task / NN, i = task % NN;
        int col = h * 64 + lane;
        const float* fr = flat + i * 15;
        float hv = 0.f;
#pragma unroll
        for (int f = 0; f < 15; ++f) hv += fr[f] * W1[f * 192 + col];
        h1[i * 192 + col] = hv;                // single h1 pass
        float ps = hv * as1[col], pt = hv * ad1[col];
#pragma unroll
        for (int off = 32; off; off >>= 1) { ps += __shfl_xor(ps, off); pt += __shfl_xor(pt, off); }
        if (lane == 0) { s1[h * NN + i] = ps; t1[h * NN + i] = pt; }
    }
}

// ---------- krank: partial rank counts via 64-bit composite keys, plain stores. grid (38,3,8) ----------
__global__ __launch_bounds__(256) void krank(const float* __restrict__ s, const float* __restrict__ t,
                                             int* __restrict__ partial) {
    __shared__ __align__(16) ull ts[KLEN];
    const int h = blockIdx.y, kc = blockIdx.z;
    const float* tp = t + h * NN + kc * KLEN;
    for (int k = threadIdx.x; k < KLEN; k += 256)
        ts[k] = ((ull)fkey(tp[k]) << 32) | (unsigned)k;
    __syncthreads();
    int q = blockIdx.x * 256 + threadIdx.x;
    if (q >= 2 * NN) return;
    ull uq;
    if (q < NN) {
        int tb = q - kc * KLEN;
        int tbc = tb < 0 ? 0 : (tb > KLEN ? KLEN : tb);
        uq = ((ull)fkey(t[h * NN + q]) << 32) | (unsigned)tbc;
    } else {
        uq = ((ull)fkey(-s[h * NN + q - NN]) << 32) | (unsigned)KLEN;
    }
    int cnt = 0;
#pragma unroll 4
    for (int k = 0; k < KLEN; k += 2) {
        ulonglong2 v = *(const ulonglong2*)&ts[k];   // wave-uniform LDS broadcast
        cnt += (v.x < uq);
        cnt += (v.y < uq);
    }
    partial[(kc * 3 + h) * (2 * NN) + q] = cnt;
}

// ---------- ksc1: sum partials -> scatter inv/e1s/e2s (t) or write rks (s). grid 113 ----------
__global__ __launch_bounds__(256) void ksc1(const float* __restrict__ t, const int* __restrict__ partial,
                                            int* __restrict__ inv, float* __restrict__ e1s,
                                            float* __restrict__ e2s, int* __restrict__ rks) {
    int idx = blockIdx.x * 256 + threadIdx.x;
    if (idx >= 3 * 2 * NN) return;
    int h = idx / (2 * NN), q = idx % (2 * NN);
    int sum = 0;
#pragma unroll
    for (int kc = 0; kc < 8; ++kc) sum += partial[(kc * 3 + h) * (2 * NN) + q];
    if (q < NN) {
        float tv = t[h * NN + q];
        inv[h * NN + sum] = q;
        e1s[h * NN + sum] = __expf(tv);
        e2s[h * NN + sum] = __expf(0.2f * tv);
    } else {
        rks[h * NN + q - NN] = sum;
    }
}

// ---------- phA: chunk totals. grid (NC/PACK, 3), PACK*Dd == 256 ----------
template <int Dd, int HD, int PACK>
__global__ __launch_bounds__(256) void phA(const float* __restrict__ hsrc, const int* __restrict__ inv,
                                           const float* __restrict__ e1s, const float* __restrict__ e2s,
                                           float* __restrict__ T1, float* __restrict__ T2) {
    __shared__ int inv_l[PACK * CL];
    __shared__ float w1s[PACK * CL], w2s[PACK * CL];
    const int h = blockIdx.y, tid = threadIdx.x;
    const int base = blockIdx.x * (PACK * CL);
    if (tid < PACK * CL) {
        inv_l[tid] = inv[h * NN + base + tid];
        w1s[tid] = e1s[h * NN + base + tid];
        w2s[tid] = e2s[h * NN + base + tid];
    }
    __syncthreads();
    const int sub = tid / Dd, d = tid % Dd;
    const int c = blockIdx.x * PACK + sub;
    float a1 = 0.f, a2 = 0.f;
#pragma unroll
    for (int p = 0; p < CL; ++p) {
        int j = inv_l[sub * CL + p];
        float hv = hsrc[(size_t)j * HD + h * Dd + d];
        a1 += w1s[sub * CL + p] * hv;
        a2 += w2s[sub * CL + p] * hv;
    }
    T1[(h * NC + c) * Dd + d] = a1;
    T2[(h * NC + c) * Dd + d] = a2;
}

// ---------- phBden: PARALLEL Tot scans (segmented, 8x30) + denominator scans ----------
// blocks [0, 6*G): one per (h, dir, 32-wide d-group); blocks [6*G, 6*G+3): den scans per head.
template <int Dd>
__global__ __launch_bounds__(256) void phBden(const float* __restrict__ T1, const float* __restrict__ T2,
                                              const float* __restrict__ e1s, const float* __restrict__ e2s,
                                              float* __restrict__ O1, float* __restrict__ O2,
                                              float* __restrict__ DenS1, float* __restrict__ DenP2) {
    constexpr int G = Dd / 32;
    constexpr int NSCAN = 6 * G;
    __shared__ __align__(16) float smem[9608];      // union: scan{ls 7680 + sbd 512} | den{l1 4800, l2 4800, wsum 8}
    const int tid = threadIdx.x;
    if (blockIdx.x < NSCAN) {
        float (*ls)[32] = (float(*)[32])smem;        // [240][32]
        double* sbd = (double*)(smem + 7680);        // [8][32] segment sums
        const int b = blockIdx.x;
        const int h = b % 3, rest = b / 3, dir = rest & 1, dg = rest >> 1;
        const float* T = dir ? T2 : T1;
        for (int idx = tid; idx < NC * 32; idx += 256) {
            int c = idx >> 5, dl = idx & 31;
            ls[c][dl] = T[(h * NC + c) * Dd + dg * 32 + dl];
        }
        __syncthreads();
        const int seg = tid >> 5, dl = tid & 31;     // 8 segments x 32 d-lanes
        double ssum = 0.0;
#pragma unroll
        for (int k = 0; k < 30; ++k) ssum += (double)ls[seg * 30 + k][dl];
        sbd[seg * 32 + dl] = ssum;
        __syncthreads();
        double off = 0.0;
        if (dir == 0) { for (int k = seg + 1; k < 8; ++k) off += sbd[k * 32 + dl]; }
        else          { for (int k = 0; k < seg; ++k)     off += sbd[k * 32 + dl]; }
        float* O = dir ? O2 : O1;
        const int d = dg * 32 + dl;
        double r = off;
        if (dir == 0) {                              // exclusive suffix of T1
#pragma unroll
            for (int k = 29; k >= 0; --k) {
                int c = seg * 30 + k;
                O[(h * NC + c) * Dd + d] = (float)r;
                r += (double)ls[c][dl];
            }
        } else {                                     // exclusive prefix of T2
#pragma unroll
            for (int k = 0; k < 30; ++k) {
                int c = seg * 30 + k;
                O[(h * NC + c) * Dd + d] = (float)r;
                r += (double)ls[c][dl];
            }
        }
        return;
    }
    // denominator scan for head h (sorted e arrays, coalesced load)
    const int h = blockIdx.x - NSCAN;
    float* l1 = smem;
    float* l2 = smem + NN;
    float* wsum = smem + 9600;
    for (int k = tid; k < NN; k += 256) { l1[k] = e1s[h * NN + k]; l2[k] = e2s[h * NN + k]; }
    __syncthreads();
    const int p0 = tid * 19;
    const int cnt = (p0 < NN) ? ((NN - p0 < 19) ? NN - p0 : 19) : 0;
    float sA = 0.f, sB = 0.f;
    for (int k = 0; k < cnt; ++k) { sA += l1[p0 + k]; sB += l2[p0 + k]; }
    float iA = sA, iB = sB;
    const int lane = tid & 63, w = tid >> 6;
#pragma unroll
    for (int d2 = 1; d2 < 64; d2 <<= 1) {
        float uA = __shfl_up(iA, d2), uB = __shfl_up(iB, d2);
        if (lane >= d2) { iA += uA; iB += uB; }
    }
    if (lane == 63) { wsum[w] = iA; wsum[4 + w] = iB; }
    __syncthreads();
    float baseA = 0.f, baseB = 0.f;
    for (int k = 0; k < w; ++k) { baseA += wsum[k]; baseB += wsum[4 + k]; }
    float TA = wsum[0] + wsum[1] + wsum[2] + wsum[3];
    float rA = baseA + iA - sA;    // exclusive prefix offsets
    float rB = baseB + iB - sB;
    for (int k = 0; k < cnt; ++k) {
        int p = p0 + k;
        DenS1[h * NN1 + p] = TA - rA;   // inclusive suffix of e1
        DenP2[h * NN1 + p] = rB;        // exclusive prefix of e2
        rA += l1[p]; rB += l2[p];
    }
    if (tid == 255) {
        DenS1[h * NN1 + NN] = 0.f;
        DenP2[h * NN1 + NN] = wsum[4] + wsum[5] + wsum[6] + wsum[7];
    }
}

// ---------- phC: emit Suf1/Pre2; extra blocks (bx==NB, layer1 only) zero s2/t2 before gemm1 ----------
template <int Dd, int HD, int PACK>
__global__ __launch_bounds__(256) void phC(const float* __restrict__ hsrc, const int* __restrict__ inv,
                                           const float* __restrict__ e1s, const float* __restrict__ e2s,
                                           const float* __restrict__ O1, const float* __restrict__ O2,
                                           float* __restrict__ Suf1, float* __restrict__ Pre2,
                                           float* __restrict__ zs, float* __restrict__ zt) {
    constexpr int NB = NC / PACK;
    __shared__ int inv_l[PACK * CL];
    __shared__ float w1s[PACK * CL], w2s[PACK * CL];
    const int h = blockIdx.y, tid = threadIdx.x;
    if (blockIdx.x >= NB) {                        // zero-block (layer 1 only)
        if (zs) {
            for (int k = tid; k < NN; k += 256) { zs[h * NN + k] = 0.f; zt[h * NN + k] = 0.f; }
        }
        return;
    }
    const int base = blockIdx.x * (PACK * CL);
    if (tid < PACK * CL) {
        inv_l[tid] = inv[h * NN + base + tid];
        w1s[tid] = e1s[h * NN + base + tid];
        w2s[tid] = e2s[h * NN + base + tid];
    }
    __syncthreads();
    const int sub = tid / Dd, d = tid % Dd;
    const int c = blockIdx.x * PACK + sub;
    float hv[CL];
#pragma unroll
    for (int p = 0; p < CL; ++p) {
        int j = inv_l[sub * CL + p];
        hv[p] = hsrc[(size_t)j * HD + h * Dd + d];
    }
    float r2 = O2[(h * NC + c) * Dd + d];
#pragma unroll
    for (int p = 0; p < CL; ++p) {
        int pp = c * CL + p;
        Pre2[((size_t)(h * NN1) + pp) * Dd + d] = r2;
        r2 += w2s[sub * CL + p] * hv[p];
    }
    if (c == NC - 1) {
        Pre2[((size_t)(h * NN1) + NN) * Dd + d] = r2;
        Suf1[((size_t)(h * NN1) + NN) * Dd + d] = 0.f;
    }
    float r1 = O1[(h * NC + c) * Dd + d];
#pragma unroll
    for (int p = CL - 1; p >= 0; --p) {
        int pp = c * CL + p;
        r1 += w1s[sub * CL + p] * hv[p];
        Suf1[((size_t)(h * NN1) + pp) * Dd + d] = r1;
    }
}

// ---------- gemm1f: fused kout1-transform + h2 = ELU(h1attn) @ W2 + s2/t2 dots. grid (75,6) ----------
__global__ __launch_bounds__(256) void gemm1f(
    const float* __restrict__ s1, const int* __restrict__ rks1,
    const float* __restrict__ Suf1, const float* __restrict__ Pre2,
    const float* __restrict__ DenS1, const float* __restrict__ DenP2,
    const short* __restrict__ W2T, const float* __restrict__ as2, const float* __restrict__ ad2,
    float* __restrict__ h2, float* __restrict__ s2, float* __restrict__ t2) {
    const int mb = blockIdx.x, nb = blockIdx.y, tid = threadIdx.x;
    const int lane = tid & 63, w = tid >> 6, q = lane >> 4, mr = lane & 15;
    const int m = mb * 64 + w * 16 + mr, n0 = nb * 64, hh = nb >> 1;
    // per-row (i=m), per-head softmax coefficients (verbatim kout1 formulas)
    float A3[3], B3[3], DN3[3]; int R3[3];
#pragma unroll
    for (int h = 0; h < 3; ++h) {
        float sv = s1[h * NN + m];
        A3[h] = __expf(sv); B3[h] = __expf(0.2f * sv);
        int r = rks1[h * NN + m]; R3[h] = r;
        DN3[h] = A3[h] * DenS1[h * NN1 + r] + B3[h] * DenP2[h * NN1 + r];
    }
    f32x4 acc[4];
#pragma unroll
    for (int n = 0; n < 4; ++n) acc[n] = (f32x4){0.f, 0.f, 0.f, 0.f};
#pragma unroll
    for (int k0 = 0; k0 < 192; k0 += 32) {
        const int kk = k0 + q * 8;               // 8-aligned, stays within one 64-wide head block
        const int h = kk >> 6, d0 = kk & 63;
        const size_t bp = ((size_t)(h * NN1) + R3[h]) * 64 + d0;
        f32x4 sf0 = *(const f32x4*)&Suf1[bp];
        f32x4 sf1 = *(const f32x4*)&Suf1[bp + 4];
        f32x4 pr0 = *(const f32x4*)&Pre2[bp];
        f32x4 pr1 = *(const f32x4*)&Pre2[bp + 4];
        const float a = A3[h], b = B3[h], dn = DN3[h];
        short8 af;
#pragma unroll
        for (int j = 0; j < 4; ++j) {
            float v = (a * sf0[j] + b * pr0[j]) / dn;
            v = v > 0.f ? v : (__expf(v) - 1.f);       // ELU
            af[j] = bf16rne(v);
            float v2 = (a * sf1[j] + b * pr1[j]) / dn;
            v2 = v2 > 0.f ? v2 : (__expf(v2) - 1.f);
            af[4 + j] = bf16rne(v2);
        }
#pragma unroll
        for (int n = 0; n < 4; ++n) {
            short8 bf = *(const short8*)(W2T + (size_t)(n0 + n * 16 + mr) * 192 + k0 + q * 8);
            acc[n] = __builtin_amdgcn_mfma_f32_16x16x32_bf16(af, bf, acc[n], 0, 0, 0);
        }
    }
    float pse[4] = {0.f, 0.f, 0.f, 0.f}, pte[4] = {0.f, 0.f, 0.f, 0.f};
#pragma unroll
    for (int n = 0; n < 4; ++n) {
        int col = n0 + n * 16 + mr;
        float va = as2[col], vd = ad2[col];
#pragma unroll
        for (int r = 0; r < 4; ++r) {
            int row = mb * 64 + w * 16 + q * 4 + r;
            float v = acc[n][r];
            h2[(size_t)row * 384 + col] = v;
            pse[r] += v * va;
            pte[r] += v * vd;
        }
    }
#pragma unroll
    for (int off = 1; off < 16; off <<= 1) {
#pragma unroll
        for (int r = 0; r < 4; ++r) {
            pse[r] += __shfl_xor(pse[r], off);
            pte[r] += __shfl_xor(pte[r], off);
        }
    }
    if (mr == 0) {
#pragma unroll
        for (int r = 0; r < 4; ++r) {
            int row = mb * 64 + w * 16 + q * 4 + r;
            atomicAdd(&s2[hh * NN + row], pse[r]);
            atomicAdd(&t2[hh * NN + row], pte[r]);
        }
    }
}

// ---------- TAIL2: kout2 + F1 + F2 + mean pool. grid 300 (M=16) ----------
__global__ __launch_bounds__(256) void tail2(
    const float* __restrict__ s2, const int* __restrict__ rks2,
    const float* __restrict__ Suf1, const float* __restrict__ Pre2,
    const float* __restrict__ DenS1, const float* __restrict__ DenP2,
    const float* __restrict__ flat, const short* __restrict__ P1T, const short* __restrict__ P2T,
    const float* __restrict__ b1, const float* __restrict__ b2,
    float* __restrict__ out) {
    __shared__ short g[16][168];
    __shared__ short f1[16][136];
    const int mb = blockIdx.x, tid = threadIdx.x;
    for (int e = tid; e < 16 * 160; e += 256) {   // build g tile
        int row = e / 160, c = e % 160;
        int i = mb * 16 + row;
        float v;
        if (c < 128) {
            float acc = 0.f;
#pragma unroll
            for (int h = 0; h < 3; ++h) {
                float sv = s2[h * NN + i];
                float a = __expf(sv), b = __expf(0.2f * sv);
                int r = rks2[h * NN + i];
                size_t bp = ((size_t)(h * NN1) + r) * 128 + c;
                float num = a * Suf1[bp] + b * Pre2[bp];
                float den = a * DenS1[h * NN1 + r] + b * DenP2[h * NN1 + r];
                acc += num / den;
            }
            v = acc * (1.f / 3.f);
        } else if (c < 143) v = flat[i * 15 + (c - 128)];
        else v = 0.f;
        g[row][c] = bf16rne(v);
    }
    __syncthreads();
    const int lane = tid & 63, w = tid >> 6, q = lane >> 4, mr = lane & 15;
    // GEMM1: M=16, N=128, K=160; wave w handles cols w*32..w*32+31
    f32x4 a1[2];
#pragma unroll
    for (int n = 0; n < 2; ++n) a1[n] = (f32x4){0.f, 0.f, 0.f, 0.f};
#pragma unroll
    for (int k0 = 0; k0 < 160; k0 += 32) {
        short8 af = *(const short8*)&g[mr][k0 + q * 8];
#pragma unroll
        for (int n = 0; n < 2; ++n) {
            short8 bf = *(const short8*)(P1T + (size_t)(w * 32 + n * 16 + mr) * 160 + k0 + q * 8);
            a1[n] = __builtin_amdgcn_mfma_f32_16x16x32_bf16(af, bf, a1[n], 0, 0, 0);
        }
    }
#pragma unroll
    for (int n = 0; n < 2; ++n) {
        int col = w * 32 + n * 16 + mr;
        float bv = b1[col];
#pragma unroll
        for (int r = 0; r < 4; ++r) {
            int row = q * 4 + r;
            f1[row][col] = bf16rne(fmaxf(a1[n][r] + bv, 0.f));
        }
    }
    __syncthreads();
    // GEMM2: M=16, N=64, K=128; wave w handles cols w*16..w*16+15
    f32x4 a2 = (f32x4){0.f, 0.f, 0.f, 0.f};
#pragma unroll
    for (int k0 = 0; k0 < 128; k0 += 32) {
        short8 af = *(const short8*)&f1[mr][k0 + q * 8];
        short8 bf = *(const short8*)(P2T + (size_t)(w * 16 + mr) * 128 + k0 + q * 8);
        a2 = __builtin_amdgcn_mfma_f32_16x16x32_bf16(af, bf, a2, 0, 0, 0);
    }
    float* f2f = (float*)&g[0][0];                 // reuse g LDS: 16*65*4 = 4160 B
    {
        int col = w * 16 + mr;
        float bv = b2[col];
#pragma unroll
        for (int r = 0; r < 4; ++r) {
            int row = q * 4 + r;
            f2f[row * 65 + col] = fmaxf(a2[r] + bv, 0.f);
        }
    }
    __syncthreads();
    if (tid < 64) {                                // mean pool (atomics into zeroed out)
        int d = tid;
        int b0 = (mb * 16) / 150;
        int bend = (mb * 16 + 15) / 150;
        float sa = 0.f, sb = 0.f;
        for (int row = 0; row < 16; ++row) {
            float v = f2f[row * 65 + d];
            int b = (mb * 16 + row) / 150;
            if (b == b0) sa += v; else sb += v;
        }
        atomicAdd(&out[b0 * 64 + d], sa * (1.f / 150.f));
        if (bend != b0) atomicAdd(&out[bend * 64 + d], sb * (1.f / 150.f));
    }
}

extern "C" void kernel_launch(void* const* d_in, const int* in_sizes, int n_in,
                              void* d_out, int out_size, void* d_ws, size_t ws_size,
                              hipStream_t stream) {
    const float* flat   = (const float*)d_in[0];
    const float* amask  = (const float*)d_in[1];
    const float* W1     = (const float*)d_in[2];
    const float* a_src1 = (const float*)d_in[3];
    const float* a_dst1 = (const float*)d_in[4];
    const float* W2     = (const float*)d_in[5];
    const float* a_src2 = (const float*)d_in[6];
    const float* a_dst2 = (const float*)d_in[7];
    const float* P1     = (const float*)d_in[8];
    const float* b1     = (const float*)d_in[9];
    const float* P2     = (const float*)d_in[10];
    const float* b2     = (const float*)d_in[11];
    float* out = (float*)d_out;

    char* wsb = (char*)d_ws;
    int*   partial = (int*)  (wsb + 0);         // 8*3*9600*4 = 921600
    float* s1      = (float*)(wsb + 921600);    // 57600
    float* t1      = (float*)(wsb + 979200);
    float* s2      = (float*)(wsb + 1036800);
    float* t2      = (float*)(wsb + 1094400);
    int*   rks1    = (int*)  (wsb + 1152000);   // 57600
    int*   rks2    = (int*)  (wsb + 1209600);
    float* h1      = (float*)(wsb + 1267200);   // 3686400
    int*   inv     = (int*)  (wsb + 4953600);   // 57600
    float* e1s     = (float*)(wsb + 5011200);
    float* e2s     = (float*)(wsb + 5068800);
    float* DenS1   = (float*)(wsb + 5126400);   // 57664
    float* DenP2   = (float*)(wsb + 5184064);   // 57664
    float* Tot1    = (float*)(wsb + 5241728);   // 368640
    float* Tot2    = (float*)(wsb + 5610368);
    float* Off1    = (float*)(wsb + 5979008);
    float* Off2    = (float*)(wsb + 6347648);
    float* Suf1    = (float*)(wsb + 6716288);   // 7374336
    float* Pre2    = (float*)(wsb + 14090624);  // 7374336
    float* h2      = (float*)(wsb + 21464960);  // 7372800
    short* W2T     = (short*)(wsb + 30680960);  // 147456
    short* P1T     = (short*)(wsb + 30828416);  // 40960
    short* P2T     = (short*)(wsb + 30869376);  // 16384 -> end 30885760

    prep<<<1200, 256, 0, stream>>>(flat, amask, W1, a_src1, a_dst1, W2, P1, P2,
                                   h1, s1, t1, W2T, P1T, P2T, out);
    // layer 1 (Dd=64, HD=192, PACK=4)
    krank<<<dim3(38, 3, 8), 256, 0, stream>>>(s1, t1, partial);
    ksc1<<<113, 256, 0, stream>>>(t1, partial, inv, e1s, e2s, rks1);
    phA<64, 192, 4><<<dim3(60, 3), 256, 0, stream>>>(h1, inv, e1s, e2s, Tot1, Tot2);
    phBden<64><<<15, 256, 0, stream>>>(Tot1, Tot2, e1s, e2s, Off1, Off2, DenS1, DenP2);
    phC<64, 192, 4><<<dim3(61, 3), 256, 0, stream>>>(h1, inv, e1s, e2s, Off1, Off2, Suf1, Pre2, s2, t2);
    gemm1f<<<dim3(75, 6), 256, 0, stream>>>(s1, rks1, Suf1, Pre2, DenS1, DenP2,
                                            W2T, a_src2, a_dst2, h2, s2, t2);
    // layer 2 (Dd=128, HD=384, PACK=2)
    krank<<<dim3(38, 3, 8), 256, 0, stream>>>(s2, t2, partial);
    ksc1<<<113, 256, 0, stream>>>(t2, partial, inv, e1s, e2s, rks2);
    phA<128, 384, 2><<<dim3(120, 3), 256, 0, stream>>>(h2, inv, e1s, e2s, Tot1, Tot2);
    phBden<128><<<27, 256, 0, stream>>>(Tot1, Tot2, e1s, e2s, Off1, Off2, DenS1, DenP2);
    phC<128, 384, 2><<<dim3(120, 3), 256, 0, stream>>>(h2, inv, e1s, e2s, Off1, Off2, Suf1, Pre2,
                                                       nullptr, nullptr);
    tail2<<<300, 256, 0, stream>>>(s2, rks2, Suf1, Pre2, DenS1, DenP2, flat, P1T, P2T, b1, b2, out);
}